// Round 10
// baseline (181.186 us; speedup 1.0000x reference)
//
#include <hip/hip_runtime.h>

#define B_  8
#define N_  1024
#define D_  768
#define H_  12
#define HD_ 64
#define M_  (B_ * N_)            // 8192
#define WELEM (D_ * D_)          // 589824
#define XELEM ((size_t)M_ * D_)  // 6291456

typedef _Float16 f16;
typedef f16   f16x8  __attribute__((ext_vector_type(8)));
typedef short bf16x8 __attribute__((ext_vector_type(8)));
typedef float f32x4  __attribute__((ext_vector_type(4)));
typedef unsigned int u32x4 __attribute__((ext_vector_type(4)));
typedef unsigned short u16;

__device__ __forceinline__ u16 f2bf(float f) {
    unsigned int x = __float_as_uint(f);
    return (u16)((x + 0x7fffu + ((x >> 16) & 1u)) >> 16);   // RNE
}
__device__ __forceinline__ u16 f2h(float f) {
    return __builtin_bit_cast(u16, (f16)f);                 // RNE
}
// packed f32x2 -> bf16x2 in one VALU op
__device__ __forceinline__ unsigned int cvtpk_bf16(float lo, float hi) {
    unsigned int r;
    asm("v_cvt_pk_bf16_f32 %0, %1, %2" : "=v"(r) : "v"(lo), "v"(hi));
    return r;
}
#if __has_builtin(__builtin_amdgcn_exp2f)
#define EXP2F(x) __builtin_amdgcn_exp2f(x)
#else
#define EXP2F(x) exp2f(x)
#endif

#define LOG2E_   1.4426950408889634f
#define EXPBIAS_ 28.853900817779268f   // 20 * log2(e)

// direct global->LDS DMA, 16B per lane; dst = wave-uniform base + lane*16
typedef __attribute__((address_space(3))) unsigned int       as3_u32;
typedef __attribute__((address_space(1))) const unsigned int as1_u32;
__device__ __forceinline__ void dma16(const void* g, void* l) {
    __builtin_amdgcn_global_load_lds((as1_u32*)g, (as3_u32*)l, 16, 0, 0);
}

// ---------------------------------------------------------------------------
// x (fp32, M x D) -> f16, same layout.
// ---------------------------------------------------------------------------
__global__ __launch_bounds__(256) void cvt_x(const float* __restrict__ X,
                                             u16* __restrict__ Xh) {
    int idx = blockIdx.x * 256 + threadIdx.x;
    float4 v = ((const float4*)X)[idx];
    ushort4 o = {f2h(v.x), f2h(v.y), f2h(v.z), f2h(v.w)};
    ((ushort4*)Xh)[idx] = o;
}

// ---------------------------------------------------------------------------
// W (fp32, [k][n]) -> Wt (f16, [n][k]) for all 4 weights. 64x64 tiles.
// ---------------------------------------------------------------------------
__global__ __launch_bounds__(256) void cvt_w(
    const float* __restrict__ w0, const float* __restrict__ w1,
    const float* __restrict__ w2, const float* __restrict__ w3,
    u16* __restrict__ Wt) {
    const float* W = blockIdx.y == 0 ? w0 : blockIdx.y == 1 ? w1
                   : blockIdx.y == 2 ? w2 : w3;
    u16* dst = Wt + (size_t)blockIdx.y * WELEM;
    const int t  = threadIdx.x;
    const int tk = (blockIdx.x % 12) * 64, tn = (blockIdx.x / 12) * 64;
    __shared__ __align__(16) float tile[64][68];
#pragma unroll
    for (int i = 0; i < 4; ++i) {
        int r = (t >> 4) + i * 16, c4 = (t & 15) * 4;
        float4 v = *(const float4*)(W + (size_t)(tk + r) * D_ + tn + c4);
        *(float4*)&tile[r][c4] = v;
    }
    __syncthreads();
#pragma unroll
    for (int i = 0; i < 4; ++i) {
        int nr = (t >> 4) + i * 16, kc = (t & 15) * 4;
        ushort4 o = {f2h(tile[kc + 0][nr]), f2h(tile[kc + 1][nr]),
                     f2h(tile[kc + 2][nr]), f2h(tile[kc + 3][nr])};
        *(ushort4*)(dst + (size_t)(tn + nr) * D_ + tk + kc) = o;
    }
}

// ---------------------------------------------------------------------------
// QKV projection, Z-FUSED + v2 DOUBLE-BUFFER pipeline: issue next K-step's
// 10 dma16 FIRST, then counted vmcnt(10) (waits only current step's 10; the
// new 10 ride across both barriers), barrier, 48 MFMA, barrier. The drain
// that cost the single-buffer version ~50% of its time is gone; the 48-MFMA
// region (3x the unfused R4 case where this was neutral) covers the loads.
// LDS 80 KB -> 2 blocks/CU. XCD swizzle. Q pre-scaled by log2(e).
// ---------------------------------------------------------------------------
__global__ __launch_bounds__(256, 2) void gemm_qkv(
    const u16* __restrict__ Xh, const u16* __restrict__ Wt,
    const float* __restrict__ bq, const float* __restrict__ bk,
    const float* __restrict__ bv, u16* __restrict__ Qf,
    u16* __restrict__ Kf, u16* __restrict__ Vt) {
    __shared__ __align__(16) u16 As[2][128 * 64];      // 2 x 16 KB
    __shared__ __align__(16) u16 Bs[2][3 * 64 * 64];   // 2 x 24 KB (Wq|Wk|Wv)

    const int id  = blockIdx.x;                  // 768
    const int xcd = id & 7, idx = id >> 3;       // 96 per XCD
    const int m0  = (xcd * 8 + idx / 12) * 128;  // XCD owns 8 m-panels
    const int n0  = (idx % 12) * 64;

    const int t = threadIdx.x, lane = t & 63, w = t >> 6;
    const int wm = w >> 1, wn = w & 1;
    const int quad = lane >> 4, ln = lane & 15;
    const int drow = lane >> 3, dcl = (lane & 7) ^ ((lane >> 3) & 7);

    // prologue: stage K-step 0 into buffer 0 (10 dma16 per thread)
#pragma unroll
    for (int j = 0; j < 4; ++j) {
        int i = w * 4 + j, row = i * 8 + drow;
        dma16(Xh + (size_t)(m0 + row) * D_ + dcl * 8, &As[0][i * 512]);
    }
#pragma unroll
    for (int z = 0; z < 3; ++z)
#pragma unroll
        for (int j = 0; j < 2; ++j) {
            int i = w * 2 + j, row = i * 8 + drow;
            dma16(Wt + (size_t)z * WELEM + (size_t)(n0 + row) * D_ + dcl * 8,
                  &Bs[0][z * 4096 + i * 512]);
        }

    f32x4 acc[3][4][2] = {};
#pragma unroll 2
    for (int kk = 0; kk < 12; ++kk) {
        const int cur = kk & 1;
        // issue kk+1's loads into buf^1 (its readers finished at kk-1, one
        // full barrier behind), then wait only for kk's 10 loads.
        if (kk < 11) {
            const int k1 = (kk + 1) * 64;
#pragma unroll
            for (int j = 0; j < 4; ++j) {
                int i = w * 4 + j, row = i * 8 + drow;
                dma16(Xh + (size_t)(m0 + row) * D_ + k1 + dcl * 8,
                      &As[cur ^ 1][i * 512]);
            }
#pragma unroll
            for (int z = 0; z < 3; ++z)
#pragma unroll
                for (int j = 0; j < 2; ++j) {
                    int i = w * 2 + j, row = i * 8 + drow;
                    dma16(Wt + (size_t)z * WELEM + (size_t)(n0 + row) * D_ + k1 + dcl * 8,
                          &Bs[cur ^ 1][z * 4096 + i * 512]);
                }
            asm volatile("s_waitcnt vmcnt(10)" ::: "memory");
        } else {
            asm volatile("s_waitcnt vmcnt(0)" ::: "memory");
        }
        __builtin_amdgcn_s_barrier();
        __builtin_amdgcn_sched_barrier(0);

        f16x8 a[4][2];
#pragma unroll
        for (int mt = 0; mt < 4; ++mt)
#pragma unroll
            for (int ks = 0; ks < 2; ++ks)
                a[mt][ks] = *(const f16x8*)&As[cur][(wm * 64 + mt * 16 + ln) * 64 +
                                                    (((ks * 4 + quad) ^ (ln & 7)) * 8)];
        __builtin_amdgcn_s_setprio(1);
#pragma unroll
        for (int z = 0; z < 3; ++z) {
            f16x8 b[2][2];
#pragma unroll
            for (int nt = 0; nt < 2; ++nt)
#pragma unroll
                for (int ks = 0; ks < 2; ++ks)
                    b[nt][ks] = *(const f16x8*)&Bs[cur][z * 4096 +
                                                        (wn * 32 + nt * 16 + ln) * 64 +
                                                        (((ks * 4 + quad) ^ (ln & 7)) * 8)];
#pragma unroll
            for (int mt = 0; mt < 4; ++mt)
#pragma unroll
                for (int nt = 0; nt < 2; ++nt) {
                    acc[z][mt][nt] = __builtin_amdgcn_mfma_f32_16x16x32_f16(
                        a[mt][0], b[nt][0], acc[z][mt][nt], 0, 0, 0);
                    acc[z][mt][nt] = __builtin_amdgcn_mfma_f32_16x16x32_f16(
                        a[mt][1], b[nt][1], acc[z][mt][nt], 0, 0, 0);
                }
        }
        __builtin_amdgcn_s_setprio(0);
        __builtin_amdgcn_sched_barrier(0);
        __builtin_amdgcn_s_barrier();   // all waves done reading buf[cur]
    }
    const int h = n0 >> 6;
#pragma unroll
    for (int nt = 0; nt < 2; ++nt) {
        int hd = wn * 32 + nt * 16 + ln;
        float bq_ = bq[n0 + hd], bk_ = bk[n0 + hd], bv_ = bv[n0 + hd];
#pragma unroll
        for (int mt = 0; mt < 4; ++mt) {
            int mb = m0 + wm * 64 + mt * 16 + quad * 4;
            int bb = mb >> 10, ns = mb & 1023;
#pragma unroll
            for (int r = 0; r < 4; ++r)
                Qf[(((size_t)bb * H_ + h) * N_ + ns + r) * HD_ + hd] =
                    f2h((acc[0][mt][nt][r] + bq_) * LOG2E_);
#pragma unroll
            for (int r = 0; r < 4; ++r)
                Kf[(((size_t)bb * H_ + h) * N_ + ns + r) * HD_ + hd] =
                    f2h(acc[1][mt][nt][r] + bk_);
            ushort4 o = {f2bf(acc[2][mt][nt][0] + bv_), f2bf(acc[2][mt][nt][1] + bv_),
                         f2bf(acc[2][mt][nt][2] + bv_), f2bf(acc[2][mt][nt][3] + bv_)};
            *(ushort4*)(Vt + (((size_t)bb * H_ + h) * HD_ + hd) * N_ + ns) = o;
        }
    }
}

// ---------------------------------------------------------------------------
// Flash attention, MFMA. v7 (R9-proven): SWAPPED-operand form -- P never
// touches LDS. S^T = mfma(A=K, B=Q); K rows staged in permutation so the
// PV B-operand P^T assembles lane-locally via 8 cvt_pk. O^T = mfma(V^T, P^T);
// lsum = mfma(ones, P^T). LDS 32 KB; 4 waves, QBLK=128, 768 = 3 blocks/CU.
// Pipeline: prefetch-before-wait, counted vmcnt(4), 2 barriers/kt.
// ---------------------------------------------------------------------------
__global__ __launch_bounds__(256, 3) void attn_mfma(
    const u16* __restrict__ Qg, const u16* __restrict__ Kg,
    const u16* __restrict__ Vtg, u16* __restrict__ Og) {
    __shared__ __align__(16) u16 Ks[2][64 * 64];  // f16 [key(perm)][d], d-swizzled
    __shared__ __align__(16) u16 Vs[2][64 * 64];  // bf16 [hd][key], key-swizzled

    const int t = threadIdx.x, lane = t & 63, w = t >> 6;   // w in 0..3
    const int quad = lane >> 4, ln = lane & 15;
    const int drow = lane >> 3, dcl = (lane & 7) ^ ((lane >> 3) & 7);
    const int id  = blockIdx.x;                  // 768
    const int id2 = (id & 7) * 96 + (id >> 3);
    const int bh  = id2 >> 3, qt = id2 & 7;
    const u16* Qh  = Qg  + ((size_t)bh * N_ + qt * 128) * HD_;
    const u16* Kh  = Kg  + (size_t)bh * N_ * HD_;
    const u16* Vth = Vtg + (size_t)bh * HD_ * N_;
    u16*       Oh  = Og  + ((size_t)bh * N_ + qt * 128) * HD_;

    const int rho0 = w * 16 + drow, rho1 = rho0 + 8;
    const int gm0 = 32 * (rho0 >> 5) + ((rho0 >> 4) & 1) * 4 +
                    ((rho0 >> 2) & 3) * 8 + (rho0 & 3);
    const int gm1 = 32 * (rho1 >> 5) + ((rho1 >> 4) & 1) * 4 +
                    ((rho1 >> 2) & 3) * 8 + (rho1 & 3);

    f16x8 aq[2][2];
#pragma unroll
    for (int g = 0; g < 2; ++g)
#pragma unroll
        for (int ks = 0; ks < 2; ++ks)
            aq[g][ks] = *(const f16x8*)(Qh + (size_t)(w * 32 + g * 16 + ln) * HD_ +
                                        ks * 32 + quad * 8);

    const bf16x8 pone = {0x3F80, 0x3F80, 0x3F80, 0x3F80,
                         0x3F80, 0x3F80, 0x3F80, 0x3F80};   // bf16 1.0 x8
    const f32x4 nb = {-EXPBIAS_, -EXPBIAS_, -EXPBIAS_, -EXPBIAS_};

    f32x4 oacc[2][4] = {};
    f32x4 lacc[2] = {};

    dma16(Kh + (size_t)gm0 * HD_ + dcl * 8, &Ks[0][(w * 2 + 0) * 512]);
    dma16(Kh + (size_t)gm1 * HD_ + dcl * 8, &Ks[0][(w * 2 + 1) * 512]);
    dma16(Vth + (size_t)rho0 * N_ + dcl * 8, &Vs[0][(w * 2 + 0) * 512]);
    dma16(Vth + (size_t)rho1 * N_ + dcl * 8, &Vs[0][(w * 2 + 1) * 512]);

#pragma unroll 2
    for (int kt = 0; kt < 16; ++kt) {
        const int cur = kt & 1;
        if (kt < 15) {
            const int nk = (kt + 1) * 64;
            dma16(Kh + (size_t)(nk + gm0) * HD_ + dcl * 8, &Ks[cur ^ 1][(w * 2 + 0) * 512]);
            dma16(Kh + (size_t)(nk + gm1) * HD_ + dcl * 8, &Ks[cur ^ 1][(w * 2 + 1) * 512]);
            dma16(Vth + (size_t)rho0 * N_ + nk + dcl * 8, &Vs[cur ^ 1][(w * 2 + 0) * 512]);
            dma16(Vth + (size_t)rho1 * N_ + nk + dcl * 8, &Vs[cur ^ 1][(w * 2 + 1) * 512]);
            asm volatile("s_waitcnt vmcnt(4)" ::: "memory");
        } else {
            asm volatile("s_waitcnt vmcnt(0)" ::: "memory");
        }
        __builtin_amdgcn_s_barrier();
        __builtin_amdgcn_sched_barrier(0);

        // S^T = K Q^T - bias; each K fragment feeds BOTH q-groups.
        f32x4 sf[2][4];
        __builtin_amdgcn_s_setprio(1);
#pragma unroll
        for (int nt = 0; nt < 4; ++nt) {
            f16x8 k0 = *(const f16x8*)&Ks[cur][(nt * 16 + ln) * 64 + ((quad) ^ (ln & 7)) * 8];
            f16x8 k1 = *(const f16x8*)&Ks[cur][(nt * 16 + ln) * 64 + ((4 + quad) ^ (ln & 7)) * 8];
#pragma unroll
            for (int g = 0; g < 2; ++g) {
                sf[g][nt] = __builtin_amdgcn_mfma_f32_16x16x32_f16(k0, aq[g][0], nb, 0, 0, 0);
                sf[g][nt] = __builtin_amdgcn_mfma_f32_16x16x32_f16(k1, aq[g][1], sf[g][nt], 0, 0, 0);
            }
        }
        __builtin_amdgcn_s_setprio(0);

        // p = exp2(s'); assemble PV B-operand P^T lane-locally (8 cvt_pk/group)
        bf16x8 pb[2][2];
#pragma unroll
        for (int g = 0; g < 2; ++g)
#pragma unroll
            for (int c = 0; c < 2; ++c) {
                unsigned int p0 = cvtpk_bf16(EXP2F(sf[g][2 * c][0]), EXP2F(sf[g][2 * c][1]));
                unsigned int p1 = cvtpk_bf16(EXP2F(sf[g][2 * c][2]), EXP2F(sf[g][2 * c][3]));
                unsigned int p2 = cvtpk_bf16(EXP2F(sf[g][2 * c + 1][0]), EXP2F(sf[g][2 * c + 1][1]));
                unsigned int p3 = cvtpk_bf16(EXP2F(sf[g][2 * c + 1][2]), EXP2F(sf[g][2 * c + 1][3]));
                u32x4 pk = {p0, p1, p2, p3};
                pb[g][c] = __builtin_bit_cast(bf16x8, pk);
            }

        // O^T += V^T P^T; lsum = ones x P^T. V fragments feed both q-groups.
        __builtin_amdgcn_s_setprio(1);
#pragma unroll
        for (int g = 0; g < 2; ++g) {
            lacc[g] = __builtin_amdgcn_mfma_f32_16x16x32_bf16(pone, pb[g][0], lacc[g], 0, 0, 0);
            lacc[g] = __builtin_amdgcn_mfma_f32_16x16x32_bf16(pone, pb[g][1], lacc[g], 0, 0, 0);
        }
#pragma unroll
        for (int nt = 0; nt < 4; ++nt) {
            bf16x8 v0 = *(const bf16x8*)&Vs[cur][(nt * 16 + ln) * 64 +
                                                 ((quad ^ (ln & 7)) * 8)];
            bf16x8 v1 = *(const bf16x8*)&Vs[cur][(nt * 16 + ln) * 64 +
                                                 (((4 + quad) ^ (ln & 7)) * 8)];
#pragma unroll
            for (int g = 0; g < 2; ++g) {
                oacc[g][nt] = __builtin_amdgcn_mfma_f32_16x16x32_bf16(
                    v0, pb[g][0], oacc[g][nt], 0, 0, 0);
                oacc[g][nt] = __builtin_amdgcn_mfma_f32_16x16x32_bf16(
                    v1, pb[g][1], oacc[g][nt], 0, 0, 0);
            }
        }
        __builtin_amdgcn_s_setprio(0);
        __builtin_amdgcn_sched_barrier(0);
        __builtin_amdgcn_s_barrier();   // all waves done reading buf[cur]
    }

    const float sc = 0.036084391824351615f;  // 1/sqrt(768), AFTER softmax
#pragma unroll
    for (int g = 0; g < 2; ++g) {
        float inv = sc / lacc[g][0];
        u16* orow = Oh + (size_t)(w * 32 + g * 16 + ln) * HD_ + quad * 4;
#pragma unroll
        for (int nt = 0; nt < 4; ++nt) {
            ushort4 o = {f2h(oacc[g][nt][0] * inv), f2h(oacc[g][nt][1] * inv),
                         f2h(oacc[g][nt][2] * inv), f2h(oacc[g][nt][3] * inv)};
            *(ushort4*)(orow + nt * 16) = o;
        }
    }
}

// ---------------------------------------------------------------------------
// Output projection: out = O @ Wo + bo. 128x64 single-buffer (R1-proven)
// + XCD swizzle. 768 = 3 blocks/CU.
// ---------------------------------------------------------------------------
__global__ __launch_bounds__(256) void gemm_out(
    const u16* __restrict__ Ob, const u16* __restrict__ Wto,
    const float* __restrict__ bias, float* __restrict__ Out) {
    __shared__ __align__(16) u16 As[128 * 64];
    __shared__ __align__(16) u16 Bs[64 * 64];

    const int id  = blockIdx.x;                  // 768
    const int id2 = (id & 7) * 96 + (id >> 3);
    const int m0  = (id2 / 12) * 128, n0 = (id2 % 12) * 64;

    const int t = threadIdx.x, lane = t & 63, w = t >> 6;
    const int wm = w >> 1, wn = w & 1;
    const int quad = lane >> 4, ln = lane & 15;
    const int drow = lane >> 3, dcl = (lane & 7) ^ ((lane >> 3) & 7);

    f32x4 acc[4][2] = {};
    for (int k0 = 0; k0 < D_; k0 += 64) {
        int head = k0 >> 6;
        __syncthreads();
#pragma unroll
        for (int j = 0; j < 4; ++j) {
            int i = w * 4 + j, row = i * 8 + drow;
            int m = m0 + row, bb = m >> 10, ns = m & 1023;
            dma16(Ob + (((size_t)bb * H_ + head) * N_ + ns) * HD_ + dcl * 8, &As[i * 512]);
        }
#pragma unroll
        for (int j = 0; j < 2; ++j) {
            int i = w * 2 + j, row = i * 8 + drow;
            dma16(Wto + (size_t)(n0 + row) * D_ + k0 + dcl * 8, &Bs[i * 512]);
        }
        __syncthreads();
        f16x8 a[4][2], b[2][2];
#pragma unroll
        for (int mt = 0; mt < 4; ++mt)
#pragma unroll
            for (int ks = 0; ks < 2; ++ks)
                a[mt][ks] = *(const f16x8*)&As[(wm * 64 + mt * 16 + ln) * 64 +
                                               (((ks * 4 + quad) ^ (ln & 7)) * 8)];
#pragma unroll
        for (int nt = 0; nt < 2; ++nt)
#pragma unroll
            for (int ks = 0; ks < 2; ++ks)
                b[nt][ks] = *(const f16x8*)&Bs[(wn * 32 + nt * 16 + ln) * 64 +
                                               (((ks * 4 + quad) ^ (ln & 7)) * 8)];
#pragma unroll
        for (int mt = 0; mt < 4; ++mt)
#pragma unroll
            for (int nt = 0; nt < 2; ++nt) {
                acc[mt][nt] = __builtin_amdgcn_mfma_f32_16x16x32_f16(
                    a[mt][0], b[nt][0], acc[mt][nt], 0, 0, 0);
                acc[mt][nt] = __builtin_amdgcn_mfma_f32_16x16x32_f16(
                    a[mt][1], b[nt][1], acc[mt][nt], 0, 0, 0);
            }
    }
#pragma unroll
    for (int nt = 0; nt < 2; ++nt) {
        int n = n0 + wn * 32 + nt * 16 + ln;
        float bv_ = bias[n];
#pragma unroll
        for (int mt = 0; mt < 4; ++mt) {
            int mb = m0 + wm * 64 + mt * 16 + quad * 4;
#pragma unroll
            for (int r = 0; r < 4; ++r)
                Out[(size_t)(mb + r) * D_ + n] = acc[mt][nt][r] + bv_;
        }
    }
}

extern "C" void kernel_launch(void* const* d_in, const int* in_sizes, int n_in,
                              void* d_out, int out_size, void* d_ws, size_t ws_size,
                              hipStream_t stream) {
    const float* x  = (const float*)d_in[0];
    const float* Wq = (const float*)d_in[1];
    const float* bq = (const float*)d_in[2];
    const float* Wk = (const float*)d_in[3];
    const float* bk = (const float*)d_in[4];
    const float* Wv = (const float*)d_in[5];
    const float* bv = (const float*)d_in[6];
    const float* Wo = (const float*)d_in[7];
    const float* bo = (const float*)d_in[8];

    u16* Xh = (u16*)d_ws;                  // x f16, 12.6 MB
    u16* Wt = Xh + XELEM;                  // 4 W^T f16
    u16* Qf = Wt + 4 * (size_t)WELEM;      // Q f16 (B,H,N,HD), pre-scaled by log2e
    u16* Kf = Qf + XELEM;                  // K f16 (B,H,N,HD)
    u16* Vt = Kf + XELEM;                  // V bf16 (B,H,HD,N)
    u16* Ob = Vt + XELEM;                  // attn out f16 (B,H,N,HD)

    cvt_x<<<dim3((int)(XELEM / 4 / 256)), 256, 0, stream>>>(x, Xh);
    cvt_w<<<dim3(144, 4), 256, 0, stream>>>(Wq, Wk, Wv, Wo, Wt);
    gemm_qkv<<<dim3(768), 256, 0, stream>>>(Xh, Wt, bq, bk, bv, Qf, Kf, Vt);
    attn_mfma<<<dim3(768), 256, 0, stream>>>(Qf, Kf, Vt, Ob);
    gemm_out<<<dim3(768), 256, 0, stream>>>(
        Ob, Wt + 3 * (size_t)WELEM, bo, (float*)d_out);
}

// Round 11
// 176.341 us; speedup vs baseline: 1.0275x; 1.0275x over previous
//
#include <hip/hip_runtime.h>

#define B_  8
#define N_  1024
#define D_  768
#define H_  12
#define HD_ 64
#define M_  (B_ * N_)            // 8192
#define WELEM (D_ * D_)          // 589824
#define XELEM ((size_t)M_ * D_)  // 6291456

typedef _Float16 f16;
typedef f16   f16x8  __attribute__((ext_vector_type(8)));
typedef short bf16x8 __attribute__((ext_vector_type(8)));
typedef float f32x4  __attribute__((ext_vector_type(4)));
typedef unsigned int u32x4 __attribute__((ext_vector_type(4)));
typedef unsigned short u16;

__device__ __forceinline__ u16 f2bf(float f) {
    unsigned int x = __float_as_uint(f);
    return (u16)((x + 0x7fffu + ((x >> 16) & 1u)) >> 16);   // RNE
}
__device__ __forceinline__ u16 f2h(float f) {
    return __builtin_bit_cast(u16, (f16)f);                 // RNE
}
// packed f32x2 -> bf16x2 in one VALU op
__device__ __forceinline__ unsigned int cvtpk_bf16(float lo, float hi) {
    unsigned int r;
    asm("v_cvt_pk_bf16_f32 %0, %1, %2" : "=v"(r) : "v"(lo), "v"(hi));
    return r;
}
#if __has_builtin(__builtin_amdgcn_exp2f)
#define EXP2F(x) __builtin_amdgcn_exp2f(x)
#else
#define EXP2F(x) exp2f(x)
#endif

#define LOG2E_   1.4426950408889634f
#define EXPBIAS_ 28.853900817779268f   // 20 * log2(e)

// direct global->LDS DMA, 16B per lane; dst = wave-uniform base + lane*16
typedef __attribute__((address_space(3))) unsigned int       as3_u32;
typedef __attribute__((address_space(1))) const unsigned int as1_u32;
__device__ __forceinline__ void dma16(const void* g, void* l) {
    __builtin_amdgcn_global_load_lds((as1_u32*)g, (as3_u32*)l, 16, 0, 0);
}

// ---------------------------------------------------------------------------
// Fused input conversion: blocks [0,6144) convert x (fp32 -> f16, same
// layout); blocks [6144,6720) transpose-convert the 4 weight matrices
// ([k][n] fp32 -> [n][k] f16, 64x64 tiles). Merging deletes one launch gap
// and fills cvt_x's tail with the W blocks. Control flow is block-uniform.
// ---------------------------------------------------------------------------
__global__ __launch_bounds__(256) void cvt_xw(
    const float* __restrict__ X, u16* __restrict__ Xh,
    const float* __restrict__ w0, const float* __restrict__ w1,
    const float* __restrict__ w2, const float* __restrict__ w3,
    u16* __restrict__ Wt) {
    __shared__ __align__(16) float tile[64][68];
    const int bid = blockIdx.x;
    if (bid < 6144) {                            // ---- x path
        int idx = bid * 256 + threadIdx.x;
        float4 v = ((const float4*)X)[idx];
        ushort4 o = {f2h(v.x), f2h(v.y), f2h(v.z), f2h(v.w)};
        ((ushort4*)Xh)[idx] = o;
        return;
    }
    const int b2 = bid - 6144;                   // ---- w path (576 blocks)
    const int wy = b2 / 144, bx = b2 % 144;
    const float* W = wy == 0 ? w0 : wy == 1 ? w1 : wy == 2 ? w2 : w3;
    u16* dst = Wt + (size_t)wy * WELEM;
    const int t  = threadIdx.x;
    const int tk = (bx % 12) * 64, tn = (bx / 12) * 64;
#pragma unroll
    for (int i = 0; i < 4; ++i) {
        int r = (t >> 4) + i * 16, c4 = (t & 15) * 4;
        float4 v = *(const float4*)(W + (size_t)(tk + r) * D_ + tn + c4);
        *(float4*)&tile[r][c4] = v;
    }
    __syncthreads();
#pragma unroll
    for (int i = 0; i < 4; ++i) {
        int nr = (t >> 4) + i * 16, kc = (t & 15) * 4;
        ushort4 o = {f2h(tile[kc + 0][nr]), f2h(tile[kc + 1][nr]),
                     f2h(tile[kc + 2][nr]), f2h(tile[kc + 3][nr])};
        *(ushort4*)(dst + (size_t)(tn + nr) * D_ + tk + kc) = o;
    }
}

// ---------------------------------------------------------------------------
// QKV projection, Z-FUSED single-buffer (R9-proven, <=40.3 us): one block
// computes Q, K and V 128x64 tiles for its (m0,n0) -- As staged ONCE per
// K-step, reused for 3 W tiles. 768 blocks = 3/CU, LDS 40 KB, XCD swizzle.
// Q output pre-scaled by log2(e). [R10 dbuf variant regressed: 2 blocks/CU
// occupancy loss > drain removal -- do not re-attempt.]
// ---------------------------------------------------------------------------
__global__ __launch_bounds__(256, 3) void gemm_qkv(
    const u16* __restrict__ Xh, const u16* __restrict__ Wt,
    const float* __restrict__ bq, const float* __restrict__ bk,
    const float* __restrict__ bv, u16* __restrict__ Qf,
    u16* __restrict__ Kf, u16* __restrict__ Vt) {
    __shared__ __align__(16) u16 As[128 * 64];      // 16 KB
    __shared__ __align__(16) u16 Bs[3 * 64 * 64];   // 24 KB (Wq|Wk|Wv tiles)

    const int id  = blockIdx.x;                  // 768
    const int xcd = id & 7, idx = id >> 3;       // 96 per XCD
    const int m0  = (xcd * 8 + idx / 12) * 128;  // XCD owns 8 m-panels
    const int n0  = (idx % 12) * 64;

    const int t = threadIdx.x, lane = t & 63, w = t >> 6;
    const int wm = w >> 1, wn = w & 1;
    const int quad = lane >> 4, ln = lane & 15;
    const int drow = lane >> 3, dcl = (lane & 7) ^ ((lane >> 3) & 7);

    f32x4 acc[3][4][2] = {};
    for (int k0 = 0; k0 < D_; k0 += 64) {
        __syncthreads();
#pragma unroll
        for (int j = 0; j < 4; ++j) {
            int i = w * 4 + j, row = i * 8 + drow;
            dma16(Xh + (size_t)(m0 + row) * D_ + k0 + dcl * 8, &As[i * 512]);
        }
#pragma unroll
        for (int z = 0; z < 3; ++z)
#pragma unroll
            for (int j = 0; j < 2; ++j) {
                int i = w * 2 + j, row = i * 8 + drow;
                dma16(Wt + (size_t)z * WELEM + (size_t)(n0 + row) * D_ + k0 + dcl * 8,
                      &Bs[z * 4096 + i * 512]);
            }
        __syncthreads();
        f16x8 a[4][2];
#pragma unroll
        for (int mt = 0; mt < 4; ++mt)
#pragma unroll
            for (int ks = 0; ks < 2; ++ks)
                a[mt][ks] = *(const f16x8*)&As[(wm * 64 + mt * 16 + ln) * 64 +
                                               (((ks * 4 + quad) ^ (ln & 7)) * 8)];
#pragma unroll
        for (int z = 0; z < 3; ++z) {
            f16x8 b[2][2];
#pragma unroll
            for (int nt = 0; nt < 2; ++nt)
#pragma unroll
                for (int ks = 0; ks < 2; ++ks)
                    b[nt][ks] = *(const f16x8*)&Bs[z * 4096 +
                                                   (wn * 32 + nt * 16 + ln) * 64 +
                                                   (((ks * 4 + quad) ^ (ln & 7)) * 8)];
#pragma unroll
            for (int mt = 0; mt < 4; ++mt)
#pragma unroll
                for (int nt = 0; nt < 2; ++nt) {
                    acc[z][mt][nt] = __builtin_amdgcn_mfma_f32_16x16x32_f16(
                        a[mt][0], b[nt][0], acc[z][mt][nt], 0, 0, 0);
                    acc[z][mt][nt] = __builtin_amdgcn_mfma_f32_16x16x32_f16(
                        a[mt][1], b[nt][1], acc[z][mt][nt], 0, 0, 0);
                }
        }
    }
    const int h = n0 >> 6;
#pragma unroll
    for (int nt = 0; nt < 2; ++nt) {
        int hd = wn * 32 + nt * 16 + ln;
        float bq_ = bq[n0 + hd], bk_ = bk[n0 + hd], bv_ = bv[n0 + hd];
#pragma unroll
        for (int mt = 0; mt < 4; ++mt) {
            int mb = m0 + wm * 64 + mt * 16 + quad * 4;
            int bb = mb >> 10, ns = mb & 1023;
#pragma unroll
            for (int r = 0; r < 4; ++r)
                Qf[(((size_t)bb * H_ + h) * N_ + ns + r) * HD_ + hd] =
                    f2h((acc[0][mt][nt][r] + bq_) * LOG2E_);
#pragma unroll
            for (int r = 0; r < 4; ++r)
                Kf[(((size_t)bb * H_ + h) * N_ + ns + r) * HD_ + hd] =
                    f2h(acc[1][mt][nt][r] + bk_);
            ushort4 o = {f2bf(acc[2][mt][nt][0] + bv_), f2bf(acc[2][mt][nt][1] + bv_),
                         f2bf(acc[2][mt][nt][2] + bv_), f2bf(acc[2][mt][nt][3] + bv_)};
            *(ushort4*)(Vt + (((size_t)bb * H_ + h) * HD_ + hd) * N_ + ns) = o;
        }
    }
}

// ---------------------------------------------------------------------------
// Flash attention, MFMA. v7 (R9-proven): SWAPPED-operand form -- P never
// touches LDS. S^T = mfma(A=K, B=Q); K rows staged in permutation so the
// PV B-operand P^T assembles lane-locally via 8 cvt_pk. O^T = mfma(V^T, P^T);
// lsum = mfma(ones, P^T). LDS 32 KB; 4 waves, QBLK=128, 768 = 3 blocks/CU.
// Pipeline: prefetch-before-wait, counted vmcnt(4), 2 barriers/kt.
// ---------------------------------------------------------------------------
__global__ __launch_bounds__(256, 3) void attn_mfma(
    const u16* __restrict__ Qg, const u16* __restrict__ Kg,
    const u16* __restrict__ Vtg, u16* __restrict__ Og) {
    __shared__ __align__(16) u16 Ks[2][64 * 64];  // f16 [key(perm)][d], d-swizzled
    __shared__ __align__(16) u16 Vs[2][64 * 64];  // bf16 [hd][key], key-swizzled

    const int t = threadIdx.x, lane = t & 63, w = t >> 6;   // w in 0..3
    const int quad = lane >> 4, ln = lane & 15;
    const int drow = lane >> 3, dcl = (lane & 7) ^ ((lane >> 3) & 7);
    const int id  = blockIdx.x;                  // 768
    const int id2 = (id & 7) * 96 + (id >> 3);
    const int bh  = id2 >> 3, qt = id2 & 7;
    const u16* Qh  = Qg  + ((size_t)bh * N_ + qt * 128) * HD_;
    const u16* Kh  = Kg  + (size_t)bh * N_ * HD_;
    const u16* Vth = Vtg + (size_t)bh * HD_ * N_;
    u16*       Oh  = Og  + ((size_t)bh * N_ + qt * 128) * HD_;

    const int rho0 = w * 16 + drow, rho1 = rho0 + 8;
    const int gm0 = 32 * (rho0 >> 5) + ((rho0 >> 4) & 1) * 4 +
                    ((rho0 >> 2) & 3) * 8 + (rho0 & 3);
    const int gm1 = 32 * (rho1 >> 5) + ((rho1 >> 4) & 1) * 4 +
                    ((rho1 >> 2) & 3) * 8 + (rho1 & 3);

    f16x8 aq[2][2];
#pragma unroll
    for (int g = 0; g < 2; ++g)
#pragma unroll
        for (int ks = 0; ks < 2; ++ks)
            aq[g][ks] = *(const f16x8*)(Qh + (size_t)(w * 32 + g * 16 + ln) * HD_ +
                                        ks * 32 + quad * 8);

    const bf16x8 pone = {0x3F80, 0x3F80, 0x3F80, 0x3F80,
                         0x3F80, 0x3F80, 0x3F80, 0x3F80};   // bf16 1.0 x8
    const f32x4 nb = {-EXPBIAS_, -EXPBIAS_, -EXPBIAS_, -EXPBIAS_};

    f32x4 oacc[2][4] = {};
    f32x4 lacc[2] = {};

    dma16(Kh + (size_t)gm0 * HD_ + dcl * 8, &Ks[0][(w * 2 + 0) * 512]);
    dma16(Kh + (size_t)gm1 * HD_ + dcl * 8, &Ks[0][(w * 2 + 1) * 512]);
    dma16(Vth + (size_t)rho0 * N_ + dcl * 8, &Vs[0][(w * 2 + 0) * 512]);
    dma16(Vth + (size_t)rho1 * N_ + dcl * 8, &Vs[0][(w * 2 + 1) * 512]);

#pragma unroll 2
    for (int kt = 0; kt < 16; ++kt) {
        const int cur = kt & 1;
        if (kt < 15) {
            const int nk = (kt + 1) * 64;
            dma16(Kh + (size_t)(nk + gm0) * HD_ + dcl * 8, &Ks[cur ^ 1][(w * 2 + 0) * 512]);
            dma16(Kh + (size_t)(nk + gm1) * HD_ + dcl * 8, &Ks[cur ^ 1][(w * 2 + 1) * 512]);
            dma16(Vth + (size_t)rho0 * N_ + nk + dcl * 8, &Vs[cur ^ 1][(w * 2 + 0) * 512]);
            dma16(Vth + (size_t)rho1 * N_ + nk + dcl * 8, &Vs[cur ^ 1][(w * 2 + 1) * 512]);
            asm volatile("s_waitcnt vmcnt(4)" ::: "memory");
        } else {
            asm volatile("s_waitcnt vmcnt(0)" ::: "memory");
        }
        __builtin_amdgcn_s_barrier();
        __builtin_amdgcn_sched_barrier(0);

        // S^T = K Q^T - bias; each K fragment feeds BOTH q-groups.
        f32x4 sf[2][4];
        __builtin_amdgcn_s_setprio(1);
#pragma unroll
        for (int nt = 0; nt < 4; ++nt) {
            f16x8 k0 = *(const f16x8*)&Ks[cur][(nt * 16 + ln) * 64 + ((quad) ^ (ln & 7)) * 8];
            f16x8 k1 = *(const f16x8*)&Ks[cur][(nt * 16 + ln) * 64 + ((4 + quad) ^ (ln & 7)) * 8];
#pragma unroll
            for (int g = 0; g < 2; ++g) {
                sf[g][nt] = __builtin_amdgcn_mfma_f32_16x16x32_f16(k0, aq[g][0], nb, 0, 0, 0);
                sf[g][nt] = __builtin_amdgcn_mfma_f32_16x16x32_f16(k1, aq[g][1], sf[g][nt], 0, 0, 0);
            }
        }
        __builtin_amdgcn_s_setprio(0);

        // p = exp2(s'); assemble PV B-operand P^T lane-locally (8 cvt_pk/group)
        bf16x8 pb[2][2];
#pragma unroll
        for (int g = 0; g < 2; ++g)
#pragma unroll
            for (int c = 0; c < 2; ++c) {
                unsigned int p0 = cvtpk_bf16(EXP2F(sf[g][2 * c][0]), EXP2F(sf[g][2 * c][1]));
                unsigned int p1 = cvtpk_bf16(EXP2F(sf[g][2 * c][2]), EXP2F(sf[g][2 * c][3]));
                unsigned int p2 = cvtpk_bf16(EXP2F(sf[g][2 * c + 1][0]), EXP2F(sf[g][2 * c + 1][1]));
                unsigned int p3 = cvtpk_bf16(EXP2F(sf[g][2 * c + 1][2]), EXP2F(sf[g][2 * c + 1][3]));
                u32x4 pk = {p0, p1, p2, p3};
                pb[g][c] = __builtin_bit_cast(bf16x8, pk);
            }

        // O^T += V^T P^T; lsum = ones x P^T. V fragments feed both q-groups.
        __builtin_amdgcn_s_setprio(1);
#pragma unroll
        for (int g = 0; g < 2; ++g) {
            lacc[g] = __builtin_amdgcn_mfma_f32_16x16x32_bf16(pone, pb[g][0], lacc[g], 0, 0, 0);
            lacc[g] = __builtin_amdgcn_mfma_f32_16x16x32_bf16(pone, pb[g][1], lacc[g], 0, 0, 0);
        }
#pragma unroll
        for (int nt = 0; nt < 4; ++nt) {
            bf16x8 v0 = *(const bf16x8*)&Vs[cur][(nt * 16 + ln) * 64 +
                                                 ((quad ^ (ln & 7)) * 8)];
            bf16x8 v1 = *(const bf16x8*)&Vs[cur][(nt * 16 + ln) * 64 +
                                                 (((4 + quad) ^ (ln & 7)) * 8)];
#pragma unroll
            for (int g = 0; g < 2; ++g) {
                oacc[g][nt] = __builtin_amdgcn_mfma_f32_16x16x32_bf16(
                    v0, pb[g][0], oacc[g][nt], 0, 0, 0);
                oacc[g][nt] = __builtin_amdgcn_mfma_f32_16x16x32_bf16(
                    v1, pb[g][1], oacc[g][nt], 0, 0, 0);
            }
        }
        __builtin_amdgcn_s_setprio(0);
        __builtin_amdgcn_sched_barrier(0);
        __builtin_amdgcn_s_barrier();   // all waves done reading buf[cur]
    }

    const float sc = 0.036084391824351615f;  // 1/sqrt(768), AFTER softmax
#pragma unroll
    for (int g = 0; g < 2; ++g) {
        float inv = sc / lacc[g][0];
        u16* orow = Oh + (size_t)(w * 32 + g * 16 + ln) * HD_ + quad * 4;
#pragma unroll
        for (int nt = 0; nt < 4; ++nt) {
            ushort4 o = {f2h(oacc[g][nt][0] * inv), f2h(oacc[g][nt][1] * inv),
                         f2h(oacc[g][nt][2] * inv), f2h(oacc[g][nt][3] * inv)};
            *(ushort4*)(orow + nt * 16) = o;
        }
    }
}

// ---------------------------------------------------------------------------
// Output projection: out = O @ Wo + bo. 128x64 single-buffer (R1-proven)
// + XCD swizzle. 768 = 3 blocks/CU.
// ---------------------------------------------------------------------------
__global__ __launch_bounds__(256) void gemm_out(
    const u16* __restrict__ Ob, const u16* __restrict__ Wto,
    const float* __restrict__ bias, float* __restrict__ Out) {
    __shared__ __align__(16) u16 As[128 * 64];
    __shared__ __align__(16) u16 Bs[64 * 64];

    const int id  = blockIdx.x;                  // 768
    const int id2 = (id & 7) * 96 + (id >> 3);
    const int m0  = (id2 / 12) * 128, n0 = (id2 % 12) * 64;

    const int t = threadIdx.x, lane = t & 63, w = t >> 6;
    const int wm = w >> 1, wn = w & 1;
    const int quad = lane >> 4, ln = lane & 15;
    const int drow = lane >> 3, dcl = (lane & 7) ^ ((lane >> 3) & 7);

    f32x4 acc[4][2] = {};
    for (int k0 = 0; k0 < D_; k0 += 64) {
        int head = k0 >> 6;
        __syncthreads();
#pragma unroll
        for (int j = 0; j < 4; ++j) {
            int i = w * 4 + j, row = i * 8 + drow;
            int m = m0 + row, bb = m >> 10, ns = m & 1023;
            dma16(Ob + (((size_t)bb * H_ + head) * N_ + ns) * HD_ + dcl * 8, &As[i * 512]);
        }
#pragma unroll
        for (int j = 0; j < 2; ++j) {
            int i = w * 2 + j, row = i * 8 + drow;
            dma16(Wto + (size_t)(n0 + row) * D_ + k0 + dcl * 8, &Bs[i * 512]);
        }
        __syncthreads();
        f16x8 a[4][2], b[2][2];
#pragma unroll
        for (int mt = 0; mt < 4; ++mt)
#pragma unroll
            for (int ks = 0; ks < 2; ++ks)
                a[mt][ks] = *(const f16x8*)&As[(wm * 64 + mt * 16 + ln) * 64 +
                                               (((ks * 4 + quad) ^ (ln & 7)) * 8)];
#pragma unroll
        for (int nt = 0; nt < 2; ++nt)
#pragma unroll
            for (int ks = 0; ks < 2; ++ks)
                b[nt][ks] = *(const f16x8*)&Bs[(wn * 32 + nt * 16 + ln) * 64 +
                                               (((ks * 4 + quad) ^ (ln & 7)) * 8)];
#pragma unroll
        for (int mt = 0; mt < 4; ++mt)
#pragma unroll
            for (int nt = 0; nt < 2; ++nt) {
                acc[mt][nt] = __builtin_amdgcn_mfma_f32_16x16x32_f16(
                    a[mt][0], b[nt][0], acc[mt][nt], 0, 0, 0);
                acc[mt][nt] = __builtin_amdgcn_mfma_f32_16x16x32_f16(
                    a[mt][1], b[nt][1], acc[mt][nt], 0, 0, 0);
            }
    }
#pragma unroll
    for (int nt = 0; nt < 2; ++nt) {
        int n = n0 + wn * 32 + nt * 16 + ln;
        float bv_ = bias[n];
#pragma unroll
        for (int mt = 0; mt < 4; ++mt) {
            int mb = m0 + wm * 64 + mt * 16 + quad * 4;
#pragma unroll
            for (int r = 0; r < 4; ++r)
                Out[(size_t)(mb + r) * D_ + n] = acc[mt][nt][r] + bv_;
        }
    }
}

extern "C" void kernel_launch(void* const* d_in, const int* in_sizes, int n_in,
                              void* d_out, int out_size, void* d_ws, size_t ws_size,
                              hipStream_t stream) {
    const float* x  = (const float*)d_in[0];
    const float* Wq = (const float*)d_in[1];
    const float* bq = (const float*)d_in[2];
    const float* Wk = (const float*)d_in[3];
    const float* bk = (const float*)d_in[4];
    const float* Wv = (const float*)d_in[5];
    const float* bv = (const float*)d_in[6];
    const float* Wo = (const float*)d_in[7];
    const float* bo = (const float*)d_in[8];

    u16* Xh = (u16*)d_ws;                  // x f16, 12.6 MB
    u16* Wt = Xh + XELEM;                  // 4 W^T f16
    u16* Qf = Wt + 4 * (size_t)WELEM;      // Q f16 (B,H,N,HD), pre-scaled by log2e
    u16* Kf = Qf + XELEM;                  // K f16 (B,H,N,HD)
    u16* Vt = Kf + XELEM;                  // V bf16 (B,H,HD,N)
    u16* Ob = Vt + XELEM;                  // attn out f16 (B,H,N,HD)

    cvt_xw<<<dim3(6144 + 576), 256, 0, stream>>>(x, Xh, Wq, Wk, Wv, Wo, Wt);
    gemm_qkv<<<dim3(768), 256, 0, stream>>>(Xh, Wt, bq, bk, bv, Qf, Kf, Vt);
    attn_mfma<<<dim3(768), 256, 0, stream>>>(Qf, Kf, Vt, Ob);
    gemm_out<<<dim3(768), 256, 0, stream>>>(
        Ob, Wt + 3 * (size_t)WELEM, bo, (float*)d_out);
}